// Round 4
// baseline (1638.137 us; speedup 1.0000x reference)
//
#include <hip/hip_runtime.h>
#include <hip/hip_bf16.h>

// ---------------------------------------------------------------------------
// Performer (FAVOR+) — round 7: WO-gemm fused into FFN kernel (aoffn):
// h_new = ob@wo + bo + h_old computed in-block (packed wo fragments), LN via
// intra-quad shuffle + 1KB LDS cross-wave reduce, then round-3 FFN phases.
// Saves 2 launches + ~157 MB HBM per layer.
// B=256,N=300,IN=1280,DIM=256,L=2,H=4,DH=64,MF=266,FFH=1024
// ---------------------------------------------------------------------------

#define MF 266
#define NSEQ 300
#define DIMC 256
#define NORM_QK 0.3535533905932738f   // 64^-0.25
#define KEPS 1e-4f

typedef __attribute__((ext_vector_type(8))) short bf16x8;
typedef __attribute__((ext_vector_type(4))) float f32x4;

#define MFMA16(a, b, c) __builtin_amdgcn_mfma_f32_16x16x32_bf16((a), (b), (c), 0, 0, 0)

__device__ __forceinline__ float bfbits2f(ushort u) {
  return __uint_as_float(((unsigned int)u) << 16);
}
__device__ __forceinline__ ushort f2us(float f) {
  __hip_bfloat16 b = __float2bfloat16(f);
  return *(ushort*)&b;
}
__device__ __forceinline__ float sq8(uint4 u) {
  float s = 0.f;
  const unsigned int uu[4] = {u.x, u.y, u.z, u.w};
#pragma unroll
  for (int i = 0; i < 4; i++) {
    const float a = bfbits2f((ushort)(uu[i] & 0xffff));
    const float b = bfbits2f((ushort)(uu[i] >> 16));
    s += a * a + b * b;
  }
  return s;
}
// async global->LDS, 16B per lane; LDS dst must be waveBase + lane*16 (it is:
// all staging layouts below are byte-linear in tid).
__device__ __forceinline__ void gld16(const void* g, void* l) {
  __builtin_amdgcn_global_load_lds(
      (const __attribute__((address_space(1))) unsigned int*)g,
      (__attribute__((address_space(3))) unsigned int*)l, 16, 0, 0);
}
__device__ __forceinline__ float fast_gelu(float x) {
  const float t = 0.7978845608028654f * (x + 0.044715f * x * x * x);
  const float e = __expf(2.0f * fabsf(t));          // inf-safe: th -> 1
  float th = 1.0f - 2.0f / (e + 1.0f);
  th = (t < 0.0f) ? -th : th;
  return 0.5f * x * (1.0f + th);
}

// ---------------------------------------------------------------------------
// bf16 MFMA GEMM: C[M,N] = epi(A[M,K] @ BT[N,K]^T + bias [+R])
// 128x128 tile, BK=32, 4 waves, 4x4 grid of 16x16x32 MFMAs per wave.
// Staging via global_load_lds (16B/lane); AF32=1: A is fp32, staged via VGPR.
// Grid is COL-FAST: col0 = blockIdx.x so the col-blocks sharing an A-slice
// are dispatch-adjacent -> re-reads hit L2/L3 instead of HBM.
// EPI: 0=+bias->f32 ;
//      4=QKV: no bias, out bf16 [tsel][bh][n][64], q/k prescaled by NORM_QK
// ---------------------------------------------------------------------------
template<int EPI, int OUTBF, int AF32>
__global__ __launch_bounds__(256) void gemm_mfma(
    const ushort* __restrict__ A, const float* __restrict__ Af,
    const ushort* __restrict__ BT,
    const float* __restrict__ bias, const float* __restrict__ R,
    float* __restrict__ Cf, __hip_bfloat16* __restrict__ Cb,
    ushort* __restrict__ Cq, int M, int N, int K)
{
  __shared__ ushort As[128][32];   // byte offset of [tid>>2][(tid&3)*8] == tid*16
  __shared__ ushort Bs[128][32];
  const int tid = threadIdx.x;
  const int row0 = blockIdx.y << 7, col0 = blockIdx.x << 7;
  const int w = tid >> 6, lane = tid & 63;
  const int wm = (w >> 1) << 6, wn = (w & 1) << 6;
  const int r = lane & 15, quad = lane >> 4;
  const int sr = tid >> 2, sc = (tid & 3) << 3;
  f32x4 acc[4][4];
#pragma unroll
  for (int i = 0; i < 4; i++)
#pragma unroll
    for (int j = 0; j < 4; j++) acc[i][j] = (f32x4){0.f, 0.f, 0.f, 0.f};
  const ushort* ap0 = A + (size_t)(row0 + sr) * K + sc;
  const ushort* ap1 = A + (size_t)(row0 + sr + 64) * K + sc;
  const float*  af0 = Af + (size_t)(row0 + sr) * K + sc;
  const float*  af1 = Af + (size_t)(row0 + sr + 64) * K + sc;
  const ushort* bp0 = BT + (size_t)(col0 + sr) * K + sc;
  const ushort* bp1 = BT + (size_t)(col0 + sr + 64) * K + sc;
  for (int k0 = 0; k0 < K; k0 += 32) {
    if (AF32) {
      const float4 u0 = *(const float4*)(af0 + k0);
      const float4 u1 = *(const float4*)(af0 + k0 + 4);
      const float4 u2 = *(const float4*)(af1 + k0);
      const float4 u3 = *(const float4*)(af1 + k0 + 4);
      ushort4 p0, p1, p2, p3;
      p0.x=f2us(u0.x); p0.y=f2us(u0.y); p0.z=f2us(u0.z); p0.w=f2us(u0.w);
      p1.x=f2us(u1.x); p1.y=f2us(u1.y); p1.z=f2us(u1.z); p1.w=f2us(u1.w);
      p2.x=f2us(u2.x); p2.y=f2us(u2.y); p2.z=f2us(u2.z); p2.w=f2us(u2.w);
      p3.x=f2us(u3.x); p3.y=f2us(u3.y); p3.z=f2us(u3.z); p3.w=f2us(u3.w);
      *(ushort4*)&As[sr][sc]      = p0;
      *(ushort4*)&As[sr][sc+4]    = p1;
      *(ushort4*)&As[sr+64][sc]   = p2;
      *(ushort4*)&As[sr+64][sc+4] = p3;
    } else {
      gld16(ap0 + k0, &As[sr][sc]);
      gld16(ap1 + k0, &As[sr + 64][sc]);
    }
    gld16(bp0 + k0, &Bs[sr][sc]);
    gld16(bp1 + k0, &Bs[sr + 64][sc]);
    __syncthreads();
    bf16x8 af[4], bfv[4];
#pragma unroll
    for (int i = 0; i < 4; i++) af[i]  = *(const bf16x8*)&As[wm + i*16 + r][quad << 3];
#pragma unroll
    for (int i = 0; i < 4; i++) bfv[i] = *(const bf16x8*)&Bs[wn + i*16 + r][quad << 3];
#pragma unroll
    for (int mi = 0; mi < 4; mi++)
#pragma unroll
      for (int ni = 0; ni < 4; ni++)
        acc[mi][ni] = MFMA16(af[mi], bfv[ni], acc[mi][ni]);
    __syncthreads();
  }
  // epilogue: C/D layout col=lane&15, row=quad*4+reg
#pragma unroll
  for (int mi = 0; mi < 4; mi++) {
    const int rowb = row0 + wm + mi*16 + (quad << 2);
#pragma unroll
    for (int ni = 0; ni < 4; ni++) {
      const int col = col0 + wn + ni*16 + r;
      if (EPI == 4) {
        const int tsel = col >> 8, hd = col & 255, hh = hd >> 6, d = hd & 63;
        const float sc_ = (tsel == 2) ? 1.f : NORM_QK;
#pragma unroll
        for (int j = 0; j < 4; j++) {
          const int rowj = rowb + j;
          const int bq = rowj / 300, nq = rowj - bq * 300;
          Cq[(((size_t)tsel * 1024 + (bq << 2) + hh) * 300 + nq) * 64 + d] =
              f2us(acc[mi][ni][j] * sc_);
        }
      } else {
        const float bv = bias[col];
#pragma unroll
        for (int j = 0; j < 4; j++) {
          const size_t off = (size_t)(rowb + j) * N + col;
          float vv = acc[mi][ni][j] + bv;
          if (EPI == 1) vv += R[off];
          if (OUTBF) Cb[off] = __float2bfloat16(vv);
          else       Cf[off] = vv;
        }
      }
    }
  }
}

// ---------------------------------------------------------------------------
// Pack w1T/w2T/woT into MFMA fragment order so each weight wave-load in the
// aoffn kernel is base + lane*16 (one contiguous 1KB burst).
// W1P: 32768 chunks, group g = nc*64+w*8+ks:
//      lane l <- w1T[nc*128+w*16+(l&15)][ks*32+(l>>4)*8]
// W2P: 32768 chunks, group g = nc*64+w*8+kq*2+jn:
//      lane l <- w2T[w*32+jn*16+(l&15)][nc*128+kq*32+(l>>4)*8]
// WOP: 8192 chunks,  group g = ks*16+nt:
//      lane l <- woT[nt*16+(l&15)][ks*32+(l>>4)*8]
// Total 73728 chunks -> 288 blocks.
// ---------------------------------------------------------------------------
__global__ __launch_bounds__(256) void pack_ffn(
    const ushort* __restrict__ w1T, const ushort* __restrict__ w2T,
    const ushort* __restrict__ woT,
    ushort* __restrict__ W1P, ushort* __restrict__ W2P,
    ushort* __restrict__ WOP)
{
  const int c = blockIdx.x * 256 + threadIdx.x;   // [0, 73728)
  if (c < 32768) {
    const int l = c & 63, g = c >> 6;
    const int r = l & 15, q = l >> 4;
    const int nc = g >> 6, w = (g >> 3) & 7, ks = g & 7;
    *(uint4*)(W1P + (size_t)c * 8) =
        *(const uint4*)(w1T + (size_t)(nc*128 + w*16 + r) * 256 + ks*32 + q*8);
  } else if (c < 65536) {
    const int ci = c - 32768;
    const int l = ci & 63, g = ci >> 6;
    const int r = l & 15, q = l >> 4;
    const int nc = g >> 6, w = (g >> 3) & 7, kq = (g >> 1) & 3, jn = g & 1;
    *(uint4*)(W2P + (size_t)ci * 8) =
        *(const uint4*)(w2T + (size_t)(w*32 + jn*16 + r) * 1024 + nc*128 + kq*32 + q*8);
  } else {
    const int ci = c - 65536;        // [0, 8192)
    const int l = ci & 63, g = ci >> 6;
    const int r = l & 15, q = l >> 4;
    const int ks = g >> 4, nt = g & 15;
    *(uint4*)(WOP + (size_t)ci * 8) =
        *(const uint4*)(woT + (size_t)(nt*16 + r) * 256 + ks*32 + q*8);
  }
}

// ---------------------------------------------------------------------------
// Fused attn-out + pre-norm FFN:
//   h_new = ob @ wo + bo + h_old            (WO mini-gemm, packed fragments)
//   h     = h_new + gelu(LN(h_new)@W1+b1)@W2 + b2
// One block = 64 rows, 512 threads (8 waves), 51.2+1 KB LDS -> 3 blocks/CU.
// WO: wave w owns m-tile (w&3) x col-half (w>>2): 8x f32x4 acc, 64 MFMAs,
//     LN stats via intra-quad shuffle + red1/red2 LDS cross-wave reduce
//     (var = E[x^2]-mu^2). h written once; LN'd bf16 overwrites Ys.
// FFN: identical to round-3 proven structure (8 chunks of 128 hidden).
// ---------------------------------------------------------------------------
__global__ __launch_bounds__(512, 6) void aoffn_kernel(
    float* __restrict__ h, const ushort* __restrict__ ob,
    const ushort* __restrict__ WOP, const float* __restrict__ bo,
    const ushort* __restrict__ W1P, const float* __restrict__ b1,
    const ushort* __restrict__ W2P, const float* __restrict__ b2,
    const float* __restrict__ lng, const float* __restrict__ lnb)
{
  __shared__ ushort Ys[64][264];   // ob tile, then LN'd h_new (bf16)
  __shared__ ushort Hs[64][136];
  __shared__ float red1[64][2], red2[64][2];
  const int tid = threadIdx.x, w = tid >> 6, lane = tid & 63;
  const int r = lane & 15, quad = lane >> 4;
  const int row0 = blockIdx.x << 6;

  // ---- stage ob tile [64][256] into Ys ----
  {
    const ushort* obp = ob + (size_t)row0 * DIMC;
#pragma unroll
    for (int p = 0; p < 4; p++) {
      const int i = tid + p*512;            // [0,2048) 16B chunks
      const int rr = i >> 5, cc = (i & 31) << 3;
      *(uint4*)&Ys[rr][cc] = *(const uint4*)(obp + rr*DIMC + cc);
    }
  }
  __syncthreads();

  // ---- WO mini-gemm: wave w -> rows [mt*16,+16), cols [nh*128,+128) ----
  const int mt = w & 3, nh = w >> 2;
  f32x4 wacc[8];
#pragma unroll
  for (int i = 0; i < 8; i++) wacc[i] = (f32x4){0.f, 0.f, 0.f, 0.f};
  {
    const ushort* wop = WOP + ((size_t)(nh*8) * 64 + lane) * 8;
#pragma unroll
    for (int ks = 0; ks < 8; ks++) {
      const bf16x8 a = *(const bf16x8*)&Ys[mt*16 + r][ks*32 + (quad << 3)];
#pragma unroll
      for (int nt = 0; nt < 8; nt++) {
        const bf16x8 bb = *(const bf16x8*)(wop + ((size_t)ks*16 + nt) * 512);
        wacc[nt] = MFMA16(a, bb, wacc[nt]);
      }
    }
  }
  // ---- stats: s1/s2 per row, reduce over r (intra-quad) then cross-wave ----
  {
    float s1[4] = {0.f,0.f,0.f,0.f}, s2[4] = {0.f,0.f,0.f,0.f};
#pragma unroll
    for (int nt = 0; nt < 8; nt++) {
      const int col = (nh << 7) + nt*16 + r;
      const float bv = bo[col];
#pragma unroll
      for (int j = 0; j < 4; j++) {
        const int rowj = mt*16 + (quad << 2) + j;
        const float hn = wacc[nt][j] + bv + h[(size_t)(row0 + rowj)*DIMC + col];
        s1[j] += hn; s2[j] += hn*hn;
      }
    }
#pragma unroll
    for (int off = 1; off < 16; off <<= 1)
#pragma unroll
      for (int j = 0; j < 4; j++) {
        s1[j] += __shfl_xor(s1[j], off);
        s2[j] += __shfl_xor(s2[j], off);
      }
    if (r == 0) {
#pragma unroll
      for (int j = 0; j < 4; j++) {
        const int rowj = mt*16 + (quad << 2) + j;
        red1[rowj][nh] = s1[j];
        red2[rowj][nh] = s2[j];
      }
    }
  }
  __syncthreads();   // also: all WO reads of Ys complete -> safe to overwrite
  // ---- normalize: write h_new to global, LN'd bf16 into Ys ----
  {
#pragma unroll
    for (int j = 0; j < 4; j++) {
      const int rowj = mt*16 + (quad << 2) + j;
      const float mu = (red1[rowj][0] + red1[rowj][1]) * (1.0f/256.0f);
      const float e2 = (red2[rowj][0] + red2[rowj][1]) * (1.0f/256.0f);
      const float rstd = rsqrtf(e2 - mu*mu + 1e-5f);
#pragma unroll
      for (int nt = 0; nt < 8; nt++) {
        const int col = (nh << 7) + nt*16 + r;
        const float hn = wacc[nt][j] + bo[col] + h[(size_t)(row0 + rowj)*DIMC + col];
        h[(size_t)(row0 + rowj)*DIMC + col] = hn;
        Ys[rowj][col] = f2us((hn - mu) * rstd * lng[col] + lnb[col]);
      }
    }
  }
  __syncthreads();

  // ---- FFN (round-3 structure, unchanged) ----
  f32x4 oacc[4][2];   // [mi][jn]: O rows mi*16+quad*4+j, col w*32+jn*16+r
#pragma unroll
  for (int i = 0; i < 4; i++)
#pragma unroll
    for (int j = 0; j < 2; j++) oacc[i][j] = (f32x4){0.f, 0.f, 0.f, 0.f};

  for (int nc = 0; nc < 8; nc++) {
    // ---- H-phase: HcT[kh][m], wave w owns kh in [w*16, w*16+16) ----
    f32x4 hacc[4];
#pragma unroll
    for (int i = 0; i < 4; i++) hacc[i] = (f32x4){0.f, 0.f, 0.f, 0.f};
    const ushort* w1p = W1P + ((size_t)((nc*8 + w) * 8) * 64 + lane) * 8;
#pragma unroll
    for (int ks = 0; ks < 8; ks++) {
      const bf16x8 a = *(const bf16x8*)(w1p + ks * 512);
#pragma unroll
      for (int mj = 0; mj < 4; mj++) {
        const bf16x8 y = *(const bf16x8*)&Ys[mj*16 + r][ks*32 + (quad << 3)];
        hacc[mj] = MFMA16(a, y, hacc[mj]);
      }
    }
    // gelu(+b1) -> Hs[m][kh]; D: kh = w*16+quad*4+j, m = mj*16+r
    const int khb = (w << 4) + (quad << 2);
    const float4 bv = *(const float4*)(b1 + nc*128 + khb);
#pragma unroll
    for (int mj = 0; mj < 4; mj++) {
      ushort4 hv;
      hv.x = f2us(fast_gelu(hacc[mj][0] + bv.x));
      hv.y = f2us(fast_gelu(hacc[mj][1] + bv.y));
      hv.z = f2us(fast_gelu(hacc[mj][2] + bv.z));
      hv.w = f2us(fast_gelu(hacc[mj][3] + bv.w));
      *(ushort4*)&Hs[mj*16 + r][khb] = hv;
    }
    __syncthreads();
    // ---- O-phase: wave w owns n in [w*32, w*32+32) ----
    const ushort* w2p = W2P + ((size_t)((nc*8 + w) * 8) * 64 + lane) * 8;
#pragma unroll
    for (int kq = 0; kq < 4; kq++) {
      bf16x8 hf[4];
#pragma unroll
      for (int mi = 0; mi < 4; mi++)
        hf[mi] = *(const bf16x8*)&Hs[mi*16 + r][kq*32 + (quad << 3)];
#pragma unroll
      for (int jn = 0; jn < 2; jn++) {
        const bf16x8 bb = *(const bf16x8*)(w2p + (kq*2 + jn) * 512);
#pragma unroll
        for (int mi = 0; mi < 4; mi++)
          oacc[mi][jn] = MFMA16(hf[mi], bb, oacc[mi][jn]);
      }
    }
    __syncthreads();
  }

  // ---- epilogue: h += O + b2 (h holds h_new; RAW ordered by barriers) ----
#pragma unroll
  for (int mi = 0; mi < 4; mi++) {
    const int mbase = row0 + mi*16 + (quad << 2);
#pragma unroll
    for (int jn = 0; jn < 2; jn++) {
      const int n = (w << 5) + jn*16 + r;
      const float b2v = b2[n];
#pragma unroll
      for (int jj = 0; jj < 4; jj++) {
        float* hp = h + (size_t)(mbase + jj) * DIMC + n;
        *hp += oacc[mi][jn][jj] + b2v;
      }
    }
  }
}

// ---------------------------------------------------------------------------
__global__ __launch_bounds__(256) void cast_bf16_kernel(
    const float* __restrict__ in, ushort* __restrict__ out, int n4)
{
  const int i = blockIdx.x * 256 + threadIdx.x;
  if (i >= n4) return;
  const float4 v = ((const float4*)in)[i];
  ushort4 rr;
  rr.x = f2us(v.x); rr.y = f2us(v.y); rr.z = f2us(v.z); rr.w = f2us(v.w);
  ((ushort4*)out)[i] = rr;
}

// All 13 weight transpose-casts in one launch. [R][C] fp32 -> [C][R] bf16.
struct TSeg { const float* src; ushort* dst; int R; int C; int base; };
struct TTab { TSeg s[13]; };
__global__ __launch_bounds__(256) void tcast_all(TTab tab) {
  __shared__ float t[32][33];
  const int bid = blockIdx.x;
  int si = 0;
#pragma unroll
  for (int i = 1; i < 13; i++) if (bid >= tab.s[i].base) si = i;
  const float* src = tab.s[si].src;
  ushort* dst = tab.s[si].dst;
  const int R = tab.s[si].R, C = tab.s[si].C;
  const int local = bid - tab.s[si].base;
  const int cw = C >> 5;
  const int c0 = (local % cw) << 5, r0 = (local / cw) << 5;
  const int tx = threadIdx.x & 31, ty = threadIdx.x >> 5;
#pragma unroll
  for (int i = 0; i < 32; i += 8)
    t[ty + i][tx] = src[(size_t)(r0 + ty + i) * C + c0 + tx];
  __syncthreads();
#pragma unroll
  for (int i = 0; i < 32; i += 8)
    dst[(size_t)(c0 + ty + i) * R + r0 + tx] = f2us(t[tx][ty + i]);
}

// LayerNorm over last dim (256), bf16 out. One wave per row, 4 rows/block.
__global__ __launch_bounds__(256) void ln_kernel(
    const float* __restrict__ x, const float* __restrict__ g,
    const float* __restrict__ b, __hip_bfloat16* __restrict__ y)
{
  const int wid = threadIdx.x >> 6, lane = threadIdx.x & 63;
  const int row = blockIdx.x * 4 + wid;
  const float* xr = x + (size_t)row * DIMC;
  float v[4];
  float s = 0.f;
#pragma unroll
  for (int i = 0; i < 4; i++) { v[i] = xr[lane + 64*i]; s += v[i]; }
#pragma unroll
  for (int off = 32; off; off >>= 1) s += __shfl_xor(s, off);
  const float mu = s * (1.0f/256.0f);
  float var = 0.f;
#pragma unroll
  for (int i = 0; i < 4; i++) { const float d = v[i] - mu; var += d*d; }
#pragma unroll
  for (int off = 32; off; off >>= 1) var += __shfl_xor(var, off);
  const float rstd = rsqrtf(var * (1.0f/256.0f) + 1e-5f);
  __hip_bfloat16* yr = y + (size_t)row * DIMC;
#pragma unroll
  for (int i = 0; i < 4; i++) {
    const int c = lane + 64*i;
    yr[c] = __float2bfloat16((v[i] - mu) * rstd * g[c] + b[c]);
  }
}

// ---------------------------------------------------------------------------
// Fused FAVOR+ per (b,h): phase A (k-side, online-rescaled stab) computes
// ctx[m][d], ksum[m] entirely in LDS/registers; phase B (q-side) consumes
// them in the same block. 512 threads = 8 waves, static LDS 151,424 B.
// ---------------------------------------------------------------------------
__global__ __launch_bounds__(512) void favor_fused_kernel(
    const ushort* __restrict__ qn_all, const ushort* __restrict__ kn_all,
    const ushort* __restrict__ v_all, const ushort* __restrict__ projb,
    ushort* __restrict__ Ob)
{
  __shared__ __align__(16) uint8_t smem[151424];
  ushort (*kn_s)[72]      = (ushort(*)[72])(smem);            // [320][72] (qn in B)
  ushort (*vT_s)[328]     = (ushort(*)[328])(smem + 46080);   // [64][328] (ctxT in B)
  ushort (*proj_s)[72]    = (ushort(*)[72])(smem + 88064);    // [272][72]
  ushort (*kpT_s)[40]     = (ushort(*)[40])(smem + 127232);   // [272][40]
  ushort (*qp_s)[16][72]  = (ushort(*)[16][72])(smem + 127232); // [8][16][72] (B)
  float* diag_s = (float*)(smem + 148992);                    // [320]
  float* ksum_s = (float*)(smem + 150272);                    // [272]
  float* red_s  = (float*)(smem + 151360);                    // [8]

  const int tid = threadIdx.x, w = tid >> 6, lane = tid & 63;
  const int bh = blockIdx.x;
  const int b = bh >> 2, h = bh & 3;
  const int r = lane & 15, quad = lane >> 4;
  const int rl = lane >> 3, c8 = lane & 7;

  // ---------------- phase A staging ----------------
  {
    const ushort* knb = kn_all + (size_t)bh * 19200;
    for (int row = w*8 + rl; row < 320; row += 64) {
      uint4 u = {0u,0u,0u,0u};
      if (row < 300) u = *(const uint4*)(knb + row*64 + c8*8);
      *(uint4*)&kn_s[row][c8*8] = u;
      float s = sq8(u);
      s += __shfl_xor(s, 1); s += __shfl_xor(s, 2); s += __shfl_xor(s, 4);
      if (c8 == 0) diag_s[row] = 0.5f * s;
    }
    const ushort* vb = v_all + (size_t)bh * 19200;
    for (int row = w*8 + rl; row < 328; row += 64) {
      uint4 u = {0u,0u,0u,0u};
      if (row < 300) u = *(const uint4*)(vb + row*64 + c8*8);
      const unsigned int uu[4] = {u.x, u.y, u.z, u.w};
#pragma unroll
      for (int p = 0; p < 4; p++) {
        vT_s[c8*8 + 2*p    ][row] = (ushort)(uu[p] & 0xffff);
        vT_s[c8*8 + 2*p + 1][row] = (ushort)(uu[p] >> 16);
      }
    }
    for (int row = w*8 + rl; row < 272; row += 64) {
      uint4 u = {0u,0u,0u,0u};
      if (row < 266) u = *(const uint4*)(projb + row*64 + c8*8);
      *(uint4*)&proj_s[row][c8*8] = u;
    }
  }
  __syncthreads();

  // ---------------- phase A: online chunks of 32 n ----------------
  f32x4 cacc[9];
#pragma unroll
  for (int i = 0; i < 9; i++) cacc[i] = (f32x4){0.f,0.f,0.f,0.f};
  float ksum_acc = 0.f;
  float stab = -3.0e38f;

  for (int c = 0; c < 10; c++) {
    // dd tiles owned by this wave (<=5), chunk-local max
    f32x4 ddreg[5];
    float cmax = -3.0e38f;
#pragma unroll
    for (int ii = 0; ii < 5; ii++) {
      const int t = w + ii*8;
      if (t < 34) {
        const int tm = t >> 1, tn = c*2 + (t & 1);
        const bf16x8 a0 = *(const bf16x8*)&proj_s[tm*16 + r][quad*8];
        const bf16x8 a1 = *(const bf16x8*)&proj_s[tm*16 + r][32 + quad*8];
        const bf16x8 b0 = *(const bf16x8*)&kn_s[tn*16 + r][quad*8];
        const bf16x8 b1 = *(const bf16x8*)&kn_s[tn*16 + r][32 + quad*8];
        f32x4 acc = (f32x4){0.f,0.f,0.f,0.f};
        acc = MFMA16(a0, b0, acc);
        acc = MFMA16(a1, b1, acc);
        ddreg[ii] = acc;
        const int n = tn*16 + r;
        if (n < 300) {
#pragma unroll
          for (int j = 0; j < 4; j++) {
            const int m = tm*16 + quad*4 + j;
            if (m < 266) cmax = fmaxf(cmax, acc[j]);
          }
        }
      }
    }
#pragma unroll
    for (int off = 32; off; off >>= 1) cmax = fmaxf(cmax, __shfl_xor(cmax, off));
    if (lane == 0) red_s[w] = cmax;
    __syncthreads();
    float bmax = red_s[0];
#pragma unroll
    for (int i = 1; i < 8; i++) bmax = fmaxf(bmax, red_s[i]);
    const float stab_new = fmaxf(stab, bmax);
    const float alpha = __expf(stab - stab_new);   // chunk 0: exp(-inf)=0
    stab = stab_new;
    ksum_acc *= alpha;
#pragma unroll
    for (int i = 0; i < 9; i++)
#pragma unroll
      for (int j = 0; j < 4; j++) cacc[i][j] *= alpha;
    // kp = exp(dd - diag - stab) + eps (valid), else 0 -> kpT_s
#pragma unroll
    for (int ii = 0; ii < 5; ii++) {
      const int t = w + ii*8;
      if (t < 34) {
        const int tm = t >> 1, tnl = t & 1, tn = c*2 + tnl;
        const int n = tn*16 + r;
        const float dgn = diag_s[n];
#pragma unroll
        for (int j = 0; j < 4; j++) {
          const int m = tm*16 + quad*4 + j;
          float kp = 0.f;
          if (n < 300 && m < 266) kp = __expf(ddreg[ii][j] - dgn - stab) + KEPS;
          kpT_s[m][tnl*16 + r] = f2us(kp);
        }
      }
    }
    __syncthreads();
    // ksum row-sums + ctx MFMA accumulate
    if (tid < 272) {
      float rs = 0.f;
#pragma unroll
      for (int kk = 0; kk < 4; kk++) {
        const uint4 u = *(const uint4*)&kpT_s[tid][kk*8];
        const unsigned int uu[4] = {u.x, u.y, u.z, u.w};
#pragma unroll
        for (int p = 0; p < 4; p++)
          rs += bfbits2f((ushort)(uu[p] & 0xffff)) + bfbits2f((ushort)(uu[p] >> 16));
      }
      ksum_acc += rs;
    }
#pragma unroll
    for (int ii = 0; ii < 9; ii++) {
      const int t2 = w + ii*8;
      if (t2 < 68) {
        const int tm = t2 >> 2, td = t2 & 3;
        const bf16x8 aa = *(const bf16x8*)&kpT_s[tm*16 + r][quad*8];
        const bf16x8 bb = *(const bf16x8*)&vT_s[td*16 + r][c*32 + quad*8];
        cacc[ii] = MFMA16(aa, bb, cacc[ii]);
      }
    }
    __syncthreads();
  }

  // ---------------- A->B transition ----------------
  if (tid < 272) ksum_s[tid] = ksum_acc;
  // ctxT overlays vT (stride 328); cols m>=272 hold stale-but-finite bytes,
  // multiplied by explicit qp zeros in phase B.
#pragma unroll
  for (int ii = 0; ii < 9; ii++) {
    const int t2 = w + ii*8;
    if (t2 < 68) {
      const int tm = t2 >> 2, td = t2 & 3;
#pragma unroll
      for (int j = 0; j < 4; j++) {
        const int m = tm*16 + quad*4 + j;
        vT_s[td*16 + r][m] = f2us(cacc[ii][j]);   // ctxT[d][m]
      }
    }
  }
  // stage qn over kn_s (+ diag)
  {
    const ushort* qb = qn_all + (size_t)bh * 19200;
    for (int row = w*8 + rl; row < 320; row += 64) {
      uint4 u = {0u,0u,0u,0u};
      if (row < 300) u = *(const uint4*)(qb + row*64 + c8*8);
      *(uint4*)&kn_s[row][c8*8] = u;
      float s = sq8(u);
      s += __shfl_xor(s, 1); s += __shfl_xor(s, 2); s += __shfl_xor(s, 4);
      if (c8 == 0) diag_s[row] = 0.5f * s;
    }
  }
  __syncthreads();

  // ---------------- phase B: q-side ----------------
  for (int t = w; t < 19; t += 8) {
    const bf16x8 a0 = *(const bf16x8*)&kn_s[t*16 + r][quad*8];
    const bf16x8 a1 = *(const bf16x8*)&kn_s[t*16 + r][32 + quad*8];
    f32x4 dd[17];
#pragma unroll
    for (int tm = 0; tm < 17; tm++) {
      const bf16x8 b0 = *(const bf16x8*)&proj_s[tm*16 + r][quad*8];
      const bf16x8 b1 = *(const bf16x8*)&proj_s[tm*16 + r][32 + quad*8];
      f32x4 acc = (f32x4){0.f,0.f,0.f,0.f};
      acc = MFMA16(a0, b0, acc);
      acc = MFMA16(a1, b1, acc);
      dd[tm] = acc;
    }
    float mxj[4] = {-3.0e38f, -3.0e38f, -3.0e38f, -3.0e38f};
#pragma unroll
    for (int tm = 0; tm < 17; tm++) {
      if (tm*16 + r < 266) {
#pragma unroll
        for (int j = 0; j < 4; j++) mxj[j] = fmaxf(mxj[j], dd[tm][j]);
      }
    }
#pragma unroll
    for (int off = 1; off < 16; off <<= 1)
#pragma unroll
      for (int j = 0; j < 4; j++) mxj[j] = fmaxf(mxj[j], __shfl_xor(mxj[j], off));
    float dg[4];
#pragma unroll
    for (int j = 0; j < 4; j++) dg[j] = diag_s[t*16 + quad*4 + j];
    float den[4] = {0.f, 0.f, 0.f, 0.f};
#pragma unroll
    for (int tm = 0; tm < 17; tm++) {
      const float ks = ksum_s[tm*16 + r];
      const bool mval = (tm*16 + r < 266);
#pragma unroll
      for (int j = 0; j < 4; j++) {
        const int n = t*16 + quad*4 + j;
        float qp = 0.f;
        if (mval && n < 300) qp = __expf(dd[tm][j] - dg[j] - mxj[j]) + KEPS;
        dd[tm][j] = qp;
        den[j] += qp * ks;
      }
    }
#pragma unroll
    for (int off = 1; off < 16; off <<= 1)
#pragma unroll
      for (int j = 0; j < 4; j++) den[j] += __shfl_xor(den[j], off);
    float dinv[4];
#pragma unroll
    for (int j = 0; j < 4; j++) dinv[j] = 1.0f / den[j];

    // o = qp @ ctxT, K = 320 in 5 groups of 64 (tm>=17 zero)
    f32x4 oacc[4];
#pragma unroll
    for (int td = 0; td < 4; td++) oacc[td] = (f32x4){0.f,0.f,0.f,0.f};
#pragma unroll
    for (int g = 0; g < 5; g++) {
#pragma unroll
      for (int tt = 0; tt < 4; tt++) {
        const int tm = g*4 + tt;
#pragma unroll
        for (int j = 0; j < 4; j++) {
          const ushort us = (tm <= 16) ? f2us(dd[tm][j]) : (ushort)0;
          qp_s[w][quad*4 + j][tt*16 + r] = us;
        }
      }
#pragma unroll
      for (int s = 0; s < 2; s++) {
        const bf16x8 aa = *(const bf16x8*)&qp_s[w][r][s*32 + quad*8];
#pragma unroll
        for (int td = 0; td < 4; td++) {
          const bf16x8 bb = *(const bf16x8*)&vT_s[td*16 + r][g*64 + s*32 + quad*8];
          oacc[td] = MFMA16(aa, bb, oacc[td]);
        }
      }
    }
#pragma unroll
    for (int td = 0; td < 4; td++) {
#pragma unroll
      for (int j = 0; j < 4; j++) {
        const int n = t*16 + quad*4 + j;
        if (n < 300)
          Ob[((size_t)b*300 + n)*256 + h*64 + td*16 + r] = f2us(oacc[td][j] * dinv[j]);
      }
    }
  }
}

// ---------------------------------------------------------------------------
// Mean-pool over N, LayerNorm, 256->128 ReLU, 128->1 sigmoid. Block per batch.
// ---------------------------------------------------------------------------
__global__ __launch_bounds__(256) void head_kernel(
    const float* __restrict__ h, const float* __restrict__ hg,
    const float* __restrict__ hb, const float* __restrict__ wh1,
    const float* __restrict__ bh1, const float* __restrict__ wh2,
    const float* __restrict__ bh2, float* __restrict__ out)
{
  __shared__ float z_s[256];
  __shared__ float hid_s[128];
  __shared__ float red_s[4];
  const int b = blockIdx.x, tid = threadIdx.x;
  const float* hb_ = h + (size_t)b * NSEQ * DIMC;
  float s = 0.f;
  for (int n = 0; n < NSEQ; n++) s += hb_[(size_t)n * DIMC + tid];
  s *= (1.0f / 300.0f);
  float t1 = s;
#pragma unroll
  for (int off = 32; off; off >>= 1) t1 += __shfl_xor(t1, off);
  if ((tid & 63) == 0) red_s[tid >> 6] = t1;
  __syncthreads();
  const float mu = (red_s[0] + red_s[1] + red_s[2] + red_s[3]) * (1.0f/256.0f);
  __syncthreads();
  const float d = s - mu;
  float vv = d * d;
#pragma unroll
  for (int off = 32; off; off >>= 1) vv += __shfl_xor(vv, off);
  if ((tid & 63) == 0) red_s[tid >> 6] = vv;
  __syncthreads();
  const float var = (red_s[0] + red_s[1] + red_s[2] + red_s[3]) * (1.0f/256.0f);
  z_s[tid] = d * rsqrtf(var + 1e-5f) * hg[tid] + hb[tid];
  __syncthreads();
  if (tid < 128) {
    float acc = bh1[tid];
    for (int dd = 0; dd < 256; dd++) acc += z_s[dd] * wh1[dd * 128 + tid];
    hid_s[tid] = fmaxf(acc, 0.f);
  }
  __syncthreads();
  if (tid < 64) {
    float acc = hid_s[tid] * wh2[tid] + hid_s[tid + 64] * wh2[tid + 64];
#pragma unroll
    for (int off = 32; off; off >>= 1) acc += __shfl_xor(acc, off);
    if (tid == 0) {
      const float val = acc + bh2[0];
      out[b] = 1.0f / (1.0f + __expf(-val));
    }
  }
}

// ---------------------------------------------------------------------------
extern "C" void kernel_launch(void* const* d_in, const int* in_sizes, int n_in,
                              void* d_out, int out_size, void* d_ws, size_t ws_size,
                              hipStream_t stream) {
  const float* x    = (const float*)d_in[0];
  const float* w_in = (const float*)d_in[1];
  const float* b_in = (const float*)d_in[2];
  const float* proj = (const float*)d_in[3];
  const float* ln1g = (const float*)d_in[4];
  const float* ln1b = (const float*)d_in[5];
  const float* wq   = (const float*)d_in[6];
  const float* wk   = (const float*)d_in[7];
  const float* wv   = (const float*)d_in[8];
  const float* wo   = (const float*)d_in[9];
  const float* bo   = (const float*)d_in[10];
  const float* ln2g = (const float*)d_in[11];
  const float* ln2b = (const float*)d_in[12];
  const float* w1   = (const float*)d_in[13];
  const float* b1   = (const float*)d_in[14];
  const float* w2   = (const float*)d_in[15];
  const float* b2   = (const float*)d_in[16];
  const float* hg   = (const float*)d_in[17];
  const float* hbp  = (const float*)d_in[18];
  const float* wh1  = (const float*)d_in[19];
  const float* bh1  = (const float*)d_in[20];
  const float* wh2  = (const float*)d_in[21];
  const float* bh2  = (const float*)d_in[22];

  uint8_t* base = (uint8_t*)d_ws;
  float*  h     = (float*)(base);                        // 78,643,200 B
  ushort* yb    = (ushort*)(base + 78643200);            // 39,321,600 B
  ushort* qkv   = (ushort*)(base + 117964800);           // 117,964,800 B
  ushort* ob    = (ushort*)(base + 235929600);           // 39,321,600 B
  ushort* wbuf  = (ushort*)(base + 275251200);           //  3,801,088 B
  ushort* projb = (ushort*)(base + 279052288);           //     68,096 B
  ushort* wopb  = (ushort*)(base + 279120384);           //    262,144 B
  // aliases (disjoint lifetimes):
  ushort* qb = qkv;
  ushort* kb = qkv + 19660800;
  ushort* vb = qkv + 39321600;
  // prep-time scratch for w1T/w2T (qkv region is dead until layer-0 QKV gemm)
  ushort* scr = qkv;   // 4 x 262,144 ushorts

  ushort* w_inT = wbuf;                  // [256][1280]
  ushort* wT0   = wbuf + 327680;

  // --- prep: proj cast + all 13 weight transposes in one launch ---
  cast_bf16_kernel<<<34, 256, 0, stream>>>(proj, projb, 8512);
  TTab tab;
  int nb = 0;
  {
    int idx = 0, basem = 0;
    auto seg = [&](const float* s, ushort* d, int R, int C) {
      tab.s[idx] = TSeg{s, d, R, C, basem};
      basem += (R >> 5) * (C >> 5);
      idx++;
    };
    seg(w_in, w_inT, 1280, 256);
    for (int l = 0; l < 2; l++) {
      ushort* wl = wT0 + (size_t)l * 786432;
      seg(wq + (size_t)l*65536,  wl,          256, 256);
      seg(wk + (size_t)l*65536,  wl + 65536,  256, 256);
      seg(wv + (size_t)l*65536,  wl + 131072, 256, 256);
      seg(wo + (size_t)l*65536,  wl + 196608, 256, 256);
      // w1T/w2T go to scratch; pack_ffn permutes them into wbuf slots
      seg(w1 + (size_t)l*262144, scr + (size_t)l*524288,          256, 1024);
      seg(w2 + (size_t)l*262144, scr + (size_t)l*524288 + 262144, 1024, 256);
    }
    nb = basem;  // 1856
  }
  tcast_all<<<nb, 256, 0, stream>>>(tab);
  for (int l = 0; l < 2; l++) {
    ushort* wl = wT0 + (size_t)l * 786432;
    pack_ffn<<<288, 256, 0, stream>>>(
        scr + (size_t)l*524288, scr + (size_t)l*524288 + 262144,
        wl + 196608,
        wl + 262144, wl + 524288, wopb + (size_t)l*65536);
  }

  // --- h = x @ w_in + b_in (A read as fp32 directly; col-fast grid) ---
  gemm_mfma<0,0,1><<<dim3(2, 600), 256, 0, stream>>>(
      nullptr, x, w_inT, b_in, nullptr, h, nullptr, nullptr, 76800, 256, 1280);

  for (int l = 0; l < 2; l++) {
    ushort* wl = wT0 + (size_t)l * 786432;
    ushort* projL = projb + (size_t)l * 17024;
    ln_kernel<<<19200, 256, 0, stream>>>(h, ln1g + l*256, ln1b + l*256, (__hip_bfloat16*)yb);
    gemm_mfma<4,0,0><<<dim3(6, 600), 256, 0, stream>>>(
        yb, nullptr, wl, nullptr, nullptr, nullptr, nullptr, qkv, 76800, 768, 256);
    favor_fused_kernel<<<1024, 512, 0, stream>>>(qb, kb, vb, projL, ob);
    aoffn_kernel<<<1200, 512, 0, stream>>>(
        h, ob, wopb + (size_t)l*65536, bo + l*256,
        wl + 262144, b1 + (size_t)l*1024, wl + 524288, b2 + (size_t)l*256,
        ln2g + l*256, ln2b + l*256);
  }
  head_kernel<<<256, 256, 0, stream>>>(h, hg, hbp, wh1, bh1, wh2, bh2, (float*)d_out);
}

// Round 5
// 1569.888 us; speedup vs baseline: 1.0435x; 1.0435x over previous
//
#include <hip/hip_runtime.h>
#include <hip/hip_bf16.h>

// ---------------------------------------------------------------------------
// Performer (FAVOR+) — round 8: icache fix (#pragma unroll 1 on big outer
// loops in aoffn/favor — fully-unrolled bodies were ~100KB >> 32KB L1I,
// stalling all pipes), hn cached in regs in aoffn.
// B=256,N=300,IN=1280,DIM=256,L=2,H=4,DH=64,MF=266,FFH=1024
// ---------------------------------------------------------------------------

#define MF 266
#define NSEQ 300
#define DIMC 256
#define NORM_QK 0.3535533905932738f   // 64^-0.25
#define KEPS 1e-4f

typedef __attribute__((ext_vector_type(8))) short bf16x8;
typedef __attribute__((ext_vector_type(4))) float f32x4;

#define MFMA16(a, b, c) __builtin_amdgcn_mfma_f32_16x16x32_bf16((a), (b), (c), 0, 0, 0)

__device__ __forceinline__ float bfbits2f(ushort u) {
  return __uint_as_float(((unsigned int)u) << 16);
}
__device__ __forceinline__ ushort f2us(float f) {
  __hip_bfloat16 b = __float2bfloat16(f);
  return *(ushort*)&b;
}
__device__ __forceinline__ float sq8(uint4 u) {
  float s = 0.f;
  const unsigned int uu[4] = {u.x, u.y, u.z, u.w};
#pragma unroll
  for (int i = 0; i < 4; i++) {
    const float a = bfbits2f((ushort)(uu[i] & 0xffff));
    const float b = bfbits2f((ushort)(uu[i] >> 16));
    s += a * a + b * b;
  }
  return s;
}
// async global->LDS, 16B per lane; LDS dst must be waveBase + lane*16 (it is:
// all staging layouts below are byte-linear in tid).
__device__ __forceinline__ void gld16(const void* g, void* l) {
  __builtin_amdgcn_global_load_lds(
      (const __attribute__((address_space(1))) unsigned int*)g,
      (__attribute__((address_space(3))) unsigned int*)l, 16, 0, 0);
}
__device__ __forceinline__ float fast_gelu(float x) {
  const float t = 0.7978845608028654f * (x + 0.044715f * x * x * x);
  const float e = __expf(2.0f * fabsf(t));          // inf-safe: th -> 1
  float th = 1.0f - 2.0f / (e + 1.0f);
  th = (t < 0.0f) ? -th : th;
  return 0.5f * x * (1.0f + th);
}

// ---------------------------------------------------------------------------
// bf16 MFMA GEMM: C[M,N] = epi(A[M,K] @ BT[N,K]^T + bias [+R])
// 128x128 tile, BK=32, 4 waves, 4x4 grid of 16x16x32 MFMAs per wave.
// Staging via global_load_lds (16B/lane); AF32=1: A is fp32, staged via VGPR.
// Grid is COL-FAST: col0 = blockIdx.x so the col-blocks sharing an A-slice
// are dispatch-adjacent -> re-reads hit L2/L3 instead of HBM.
// EPI: 0=+bias->f32 ;
//      4=QKV: no bias, out bf16 [tsel][bh][n][64], q/k prescaled by NORM_QK
// ---------------------------------------------------------------------------
template<int EPI, int OUTBF, int AF32>
__global__ __launch_bounds__(256) void gemm_mfma(
    const ushort* __restrict__ A, const float* __restrict__ Af,
    const ushort* __restrict__ BT,
    const float* __restrict__ bias, const float* __restrict__ R,
    float* __restrict__ Cf, __hip_bfloat16* __restrict__ Cb,
    ushort* __restrict__ Cq, int M, int N, int K)
{
  __shared__ ushort As[128][32];   // byte offset of [tid>>2][(tid&3)*8] == tid*16
  __shared__ ushort Bs[128][32];
  const int tid = threadIdx.x;
  const int row0 = blockIdx.y << 7, col0 = blockIdx.x << 7;
  const int w = tid >> 6, lane = tid & 63;
  const int wm = (w >> 1) << 6, wn = (w & 1) << 6;
  const int r = lane & 15, quad = lane >> 4;
  const int sr = tid >> 2, sc = (tid & 3) << 3;
  f32x4 acc[4][4];
#pragma unroll
  for (int i = 0; i < 4; i++)
#pragma unroll
    for (int j = 0; j < 4; j++) acc[i][j] = (f32x4){0.f, 0.f, 0.f, 0.f};
  const ushort* ap0 = A + (size_t)(row0 + sr) * K + sc;
  const ushort* ap1 = A + (size_t)(row0 + sr + 64) * K + sc;
  const float*  af0 = Af + (size_t)(row0 + sr) * K + sc;
  const float*  af1 = Af + (size_t)(row0 + sr + 64) * K + sc;
  const ushort* bp0 = BT + (size_t)(col0 + sr) * K + sc;
  const ushort* bp1 = BT + (size_t)(col0 + sr + 64) * K + sc;
  for (int k0 = 0; k0 < K; k0 += 32) {
    if (AF32) {
      const float4 u0 = *(const float4*)(af0 + k0);
      const float4 u1 = *(const float4*)(af0 + k0 + 4);
      const float4 u2 = *(const float4*)(af1 + k0);
      const float4 u3 = *(const float4*)(af1 + k0 + 4);
      ushort4 p0, p1, p2, p3;
      p0.x=f2us(u0.x); p0.y=f2us(u0.y); p0.z=f2us(u0.z); p0.w=f2us(u0.w);
      p1.x=f2us(u1.x); p1.y=f2us(u1.y); p1.z=f2us(u1.z); p1.w=f2us(u1.w);
      p2.x=f2us(u2.x); p2.y=f2us(u2.y); p2.z=f2us(u2.z); p2.w=f2us(u2.w);
      p3.x=f2us(u3.x); p3.y=f2us(u3.y); p3.z=f2us(u3.z); p3.w=f2us(u3.w);
      *(ushort4*)&As[sr][sc]      = p0;
      *(ushort4*)&As[sr][sc+4]    = p1;
      *(ushort4*)&As[sr+64][sc]   = p2;
      *(ushort4*)&As[sr+64][sc+4] = p3;
    } else {
      gld16(ap0 + k0, &As[sr][sc]);
      gld16(ap1 + k0, &As[sr + 64][sc]);
    }
    gld16(bp0 + k0, &Bs[sr][sc]);
    gld16(bp1 + k0, &Bs[sr + 64][sc]);
    __syncthreads();
    bf16x8 af[4], bfv[4];
#pragma unroll
    for (int i = 0; i < 4; i++) af[i]  = *(const bf16x8*)&As[wm + i*16 + r][quad << 3];
#pragma unroll
    for (int i = 0; i < 4; i++) bfv[i] = *(const bf16x8*)&Bs[wn + i*16 + r][quad << 3];
#pragma unroll
    for (int mi = 0; mi < 4; mi++)
#pragma unroll
      for (int ni = 0; ni < 4; ni++)
        acc[mi][ni] = MFMA16(af[mi], bfv[ni], acc[mi][ni]);
    __syncthreads();
  }
  // epilogue: C/D layout col=lane&15, row=quad*4+reg
#pragma unroll
  for (int mi = 0; mi < 4; mi++) {
    const int rowb = row0 + wm + mi*16 + (quad << 2);
#pragma unroll
    for (int ni = 0; ni < 4; ni++) {
      const int col = col0 + wn + ni*16 + r;
      if (EPI == 4) {
        const int tsel = col >> 8, hd = col & 255, hh = hd >> 6, d = hd & 63;
        const float sc_ = (tsel == 2) ? 1.f : NORM_QK;
#pragma unroll
        for (int j = 0; j < 4; j++) {
          const int rowj = rowb + j;
          const int bq = rowj / 300, nq = rowj - bq * 300;
          Cq[(((size_t)tsel * 1024 + (bq << 2) + hh) * 300 + nq) * 64 + d] =
              f2us(acc[mi][ni][j] * sc_);
        }
      } else {
        const float bv = bias[col];
#pragma unroll
        for (int j = 0; j < 4; j++) {
          const size_t off = (size_t)(rowb + j) * N + col;
          float vv = acc[mi][ni][j] + bv;
          if (EPI == 1) vv += R[off];
          if (OUTBF) Cb[off] = __float2bfloat16(vv);
          else       Cf[off] = vv;
        }
      }
    }
  }
}

// ---------------------------------------------------------------------------
// Pack w1T/w2T/woT into MFMA fragment order so each weight wave-load in the
// aoffn kernel is base + lane*16 (one contiguous 1KB burst).
// W1P: 32768 chunks, group g = nc*64+w*8+ks:
//      lane l <- w1T[nc*128+w*16+(l&15)][ks*32+(l>>4)*8]
// W2P: 32768 chunks, group g = nc*64+w*8+kq*2+jn:
//      lane l <- w2T[w*32+jn*16+(l&15)][nc*128+kq*32+(l>>4)*8]
// WOP: 8192 chunks,  group g = ks*16+nt:
//      lane l <- woT[nt*16+(l&15)][ks*32+(l>>4)*8]
// Total 73728 chunks -> 288 blocks.
// ---------------------------------------------------------------------------
__global__ __launch_bounds__(256) void pack_ffn(
    const ushort* __restrict__ w1T, const ushort* __restrict__ w2T,
    const ushort* __restrict__ woT,
    ushort* __restrict__ W1P, ushort* __restrict__ W2P,
    ushort* __restrict__ WOP)
{
  const int c = blockIdx.x * 256 + threadIdx.x;   // [0, 73728)
  if (c < 32768) {
    const int l = c & 63, g = c >> 6;
    const int r = l & 15, q = l >> 4;
    const int nc = g >> 6, w = (g >> 3) & 7, ks = g & 7;
    *(uint4*)(W1P + (size_t)c * 8) =
        *(const uint4*)(w1T + (size_t)(nc*128 + w*16 + r) * 256 + ks*32 + q*8);
  } else if (c < 65536) {
    const int ci = c - 32768;
    const int l = ci & 63, g = ci >> 6;
    const int r = l & 15, q = l >> 4;
    const int nc = g >> 6, w = (g >> 3) & 7, kq = (g >> 1) & 3, jn = g & 1;
    *(uint4*)(W2P + (size_t)ci * 8) =
        *(const uint4*)(w2T + (size_t)(w*32 + jn*16 + r) * 1024 + nc*128 + kq*32 + q*8);
  } else {
    const int ci = c - 65536;        // [0, 8192)
    const int l = ci & 63, g = ci >> 6;
    const int r = l & 15, q = l >> 4;
    const int ks = g >> 4, nt = g & 15;
    *(uint4*)(WOP + (size_t)ci * 8) =
        *(const uint4*)(woT + (size_t)(nt*16 + r) * 256 + ks*32 + q*8);
  }
}

// ---------------------------------------------------------------------------
// Fused attn-out + pre-norm FFN:
//   h_new = ob @ wo + bo + h_old            (WO mini-gemm, packed fragments)
//   h     = h_new + gelu(LN(h_new)@W1+b1)@W2 + b2
// One block = 64 rows, 512 threads (8 waves), 51.2+1 KB LDS -> 3 blocks/CU.
// WO: wave w owns m-tile (w&3) x col-half (w>>2): 8x f32x4 acc = h_new kept
//     in regs; LN stats via intra-quad shuffle + red1/red2 LDS cross-wave
//     reduce (var = E[x^2]-mu^2). h written once; LN'd bf16 overwrites Ys.
// FFN: 8 chunks of 128 hidden; nc loop NOT unrolled (icache: body ~12KB,
//     x8 unroll blew past 32KB L1I -> uniform all-pipes-idle stall).
// ---------------------------------------------------------------------------
__global__ __launch_bounds__(512, 6) void aoffn_kernel(
    float* __restrict__ h, const ushort* __restrict__ ob,
    const ushort* __restrict__ WOP, const float* __restrict__ bo,
    const ushort* __restrict__ W1P, const float* __restrict__ b1,
    const ushort* __restrict__ W2P, const float* __restrict__ b2,
    const float* __restrict__ lng, const float* __restrict__ lnb)
{
  __shared__ ushort Ys[64][264];   // ob tile, then LN'd h_new (bf16)
  __shared__ ushort Hs[64][136];
  __shared__ float red1[64][2], red2[64][2];
  const int tid = threadIdx.x, w = tid >> 6, lane = tid & 63;
  const int r = lane & 15, quad = lane >> 4;
  const int row0 = blockIdx.x << 6;

  // ---- stage ob tile [64][256] into Ys ----
  {
    const ushort* obp = ob + (size_t)row0 * DIMC;
#pragma unroll
    for (int p = 0; p < 4; p++) {
      const int i = tid + p*512;            // [0,2048) 16B chunks
      const int rr = i >> 5, cc = (i & 31) << 3;
      *(uint4*)&Ys[rr][cc] = *(const uint4*)(obp + rr*DIMC + cc);
    }
  }
  __syncthreads();

  // ---- WO mini-gemm: wave w -> rows [mt*16,+16), cols [nh*128,+128) ----
  const int mt = w & 3, nh = w >> 2;
  f32x4 wacc[8];
#pragma unroll
  for (int i = 0; i < 8; i++) wacc[i] = (f32x4){0.f, 0.f, 0.f, 0.f};
  {
    const ushort* wop = WOP + ((size_t)(nh*8) * 64 + lane) * 8;
#pragma unroll
    for (int ks = 0; ks < 8; ks++) {
      const bf16x8 a = *(const bf16x8*)&Ys[mt*16 + r][ks*32 + (quad << 3)];
#pragma unroll
      for (int nt = 0; nt < 8; nt++) {
        const bf16x8 bb = *(const bf16x8*)(wop + ((size_t)ks*16 + nt) * 512);
        wacc[nt] = MFMA16(a, bb, wacc[nt]);
      }
    }
  }
  // ---- hn = wacc + bo + h_old kept in wacc; stats s1/s2 per row ----
  {
    float s1[4] = {0.f,0.f,0.f,0.f}, s2[4] = {0.f,0.f,0.f,0.f};
#pragma unroll
    for (int nt = 0; nt < 8; nt++) {
      const int col = (nh << 7) + nt*16 + r;
      const float bv = bo[col];
#pragma unroll
      for (int j = 0; j < 4; j++) {
        const int rowj = mt*16 + (quad << 2) + j;
        const float hn = wacc[nt][j] + bv + h[(size_t)(row0 + rowj)*DIMC + col];
        wacc[nt][j] = hn;
        s1[j] += hn; s2[j] += hn*hn;
      }
    }
#pragma unroll
    for (int off = 1; off < 16; off <<= 1)
#pragma unroll
      for (int j = 0; j < 4; j++) {
        s1[j] += __shfl_xor(s1[j], off);
        s2[j] += __shfl_xor(s2[j], off);
      }
    if (r == 0) {
#pragma unroll
      for (int j = 0; j < 4; j++) {
        const int rowj = mt*16 + (quad << 2) + j;
        red1[rowj][nh] = s1[j];
        red2[rowj][nh] = s2[j];
      }
    }
  }
  __syncthreads();   // also: all WO reads of Ys complete -> safe to overwrite
  // ---- normalize from regs: write h_new to global, LN'd bf16 into Ys ----
  {
    float mu[4], rstd[4];
#pragma unroll
    for (int j = 0; j < 4; j++) {
      const int rowj = mt*16 + (quad << 2) + j;
      mu[j] = (red1[rowj][0] + red1[rowj][1]) * (1.0f/256.0f);
      const float e2 = (red2[rowj][0] + red2[rowj][1]) * (1.0f/256.0f);
      rstd[j] = rsqrtf(e2 - mu[j]*mu[j] + 1e-5f);
    }
#pragma unroll
    for (int nt = 0; nt < 8; nt++) {
      const int col = (nh << 7) + nt*16 + r;
      const float gg = lng[col], bb = lnb[col];
#pragma unroll
      for (int j = 0; j < 4; j++) {
        const int rowj = mt*16 + (quad << 2) + j;
        const float hn = wacc[nt][j];
        h[(size_t)(row0 + rowj)*DIMC + col] = hn;
        Ys[rowj][col] = f2us((hn - mu[j]) * rstd[j] * gg + bb);
      }
    }
  }
  __syncthreads();

  // ---- FFN: 8 chunks of 128 hidden ----
  f32x4 oacc[4][2];   // [mi][jn]: O rows mi*16+quad*4+j, col w*32+jn*16+r
#pragma unroll
  for (int i = 0; i < 4; i++)
#pragma unroll
    for (int j = 0; j < 2; j++) oacc[i][j] = (f32x4){0.f, 0.f, 0.f, 0.f};

#pragma unroll 1
  for (int nc = 0; nc < 8; nc++) {
    // ---- H-phase: HcT[kh][m], wave w owns kh in [w*16, w*16+16) ----
    f32x4 hacc[4];
#pragma unroll
    for (int i = 0; i < 4; i++) hacc[i] = (f32x4){0.f, 0.f, 0.f, 0.f};
    const ushort* w1p = W1P + ((size_t)((nc*8 + w) * 8) * 64 + lane) * 8;
#pragma unroll
    for (int ks = 0; ks < 8; ks++) {
      const bf16x8 a = *(const bf16x8*)(w1p + ks * 512);
#pragma unroll
      for (int mj = 0; mj < 4; mj++) {
        const bf16x8 y = *(const bf16x8*)&Ys[mj*16 + r][ks*32 + (quad << 3)];
        hacc[mj] = MFMA16(a, y, hacc[mj]);
      }
    }
    // gelu(+b1) -> Hs[m][kh]; D: kh = w*16+quad*4+j, m = mj*16+r
    const int khb = (w << 4) + (quad << 2);
    const float4 bv = *(const float4*)(b1 + nc*128 + khb);
#pragma unroll
    for (int mj = 0; mj < 4; mj++) {
      ushort4 hv;
      hv.x = f2us(fast_gelu(hacc[mj][0] + bv.x));
      hv.y = f2us(fast_gelu(hacc[mj][1] + bv.y));
      hv.z = f2us(fast_gelu(hacc[mj][2] + bv.z));
      hv.w = f2us(fast_gelu(hacc[mj][3] + bv.w));
      *(ushort4*)&Hs[mj*16 + r][khb] = hv;
    }
    __syncthreads();
    // ---- O-phase: wave w owns n in [w*32, w*32+32) ----
    const ushort* w2p = W2P + ((size_t)((nc*8 + w) * 8) * 64 + lane) * 8;
#pragma unroll
    for (int kq = 0; kq < 4; kq++) {
      bf16x8 hf[4];
#pragma unroll
      for (int mi = 0; mi < 4; mi++)
        hf[mi] = *(const bf16x8*)&Hs[mi*16 + r][kq*32 + (quad << 3)];
#pragma unroll
      for (int jn = 0; jn < 2; jn++) {
        const bf16x8 bb = *(const bf16x8*)(w2p + (kq*2 + jn) * 512);
#pragma unroll
        for (int mi = 0; mi < 4; mi++)
          oacc[mi][jn] = MFMA16(hf[mi], bb, oacc[mi][jn]);
      }
    }
    __syncthreads();
  }

  // ---- epilogue: h += O + b2 (h holds h_new; RAW ordered by barriers) ----
#pragma unroll
  for (int mi = 0; mi < 4; mi++) {
    const int mbase = row0 + mi*16 + (quad << 2);
#pragma unroll
    for (int jn = 0; jn < 2; jn++) {
      const int n = (w << 5) + jn*16 + r;
      const float b2v = b2[n];
#pragma unroll
      for (int jj = 0; jj < 4; jj++) {
        float* hp = h + (size_t)(mbase + jj) * DIMC + n;
        *hp += oacc[mi][jn][jj] + b2v;
      }
    }
  }
}

// ---------------------------------------------------------------------------
__global__ __launch_bounds__(256) void cast_bf16_kernel(
    const float* __restrict__ in, ushort* __restrict__ out, int n4)
{
  const int i = blockIdx.x * 256 + threadIdx.x;
  if (i >= n4) return;
  const float4 v = ((const float4*)in)[i];
  ushort4 rr;
  rr.x = f2us(v.x); rr.y = f2us(v.y); rr.z = f2us(v.z); rr.w = f2us(v.w);
  ((ushort4*)out)[i] = rr;
}

// All 13 weight transpose-casts in one launch. [R][C] fp32 -> [C][R] bf16.
struct TSeg { const float* src; ushort* dst; int R; int C; int base; };
struct TTab { TSeg s[13]; };
__global__ __launch_bounds__(256) void tcast_all(TTab tab) {
  __shared__ float t[32][33];
  const int bid = blockIdx.x;
  int si = 0;
#pragma unroll
  for (int i = 1; i < 13; i++) if (bid >= tab.s[i].base) si = i;
  const float* src = tab.s[si].src;
  ushort* dst = tab.s[si].dst;
  const int R = tab.s[si].R, C = tab.s[si].C;
  const int local = bid - tab.s[si].base;
  const int cw = C >> 5;
  const int c0 = (local % cw) << 5, r0 = (local / cw) << 5;
  const int tx = threadIdx.x & 31, ty = threadIdx.x >> 5;
#pragma unroll
  for (int i = 0; i < 32; i += 8)
    t[ty + i][tx] = src[(size_t)(r0 + ty + i) * C + c0 + tx];
  __syncthreads();
#pragma unroll
  for (int i = 0; i < 32; i += 8)
    dst[(size_t)(c0 + ty + i) * R + r0 + tx] = f2us(t[tx][ty + i]);
}

// LayerNorm over last dim (256), bf16 out. One wave per row, 4 rows/block.
__global__ __launch_bounds__(256) void ln_kernel(
    const float* __restrict__ x, const float* __restrict__ g,
    const float* __restrict__ b, __hip_bfloat16* __restrict__ y)
{
  const int wid = threadIdx.x >> 6, lane = threadIdx.x & 63;
  const int row = blockIdx.x * 4 + wid;
  const float* xr = x + (size_t)row * DIMC;
  float v[4];
  float s = 0.f;
#pragma unroll
  for (int i = 0; i < 4; i++) { v[i] = xr[lane + 64*i]; s += v[i]; }
#pragma unroll
  for (int off = 32; off; off >>= 1) s += __shfl_xor(s, off);
  const float mu = s * (1.0f/256.0f);
  float var = 0.f;
#pragma unroll
  for (int i = 0; i < 4; i++) { const float d = v[i] - mu; var += d*d; }
#pragma unroll
  for (int off = 32; off; off >>= 1) var += __shfl_xor(var, off);
  const float rstd = rsqrtf(var * (1.0f/256.0f) + 1e-5f);
  __hip_bfloat16* yr = y + (size_t)row * DIMC;
#pragma unroll
  for (int i = 0; i < 4; i++) {
    const int c = lane + 64*i;
    yr[c] = __float2bfloat16((v[i] - mu) * rstd * g[c] + b[c]);
  }
}

// ---------------------------------------------------------------------------
// Fused FAVOR+ per (b,h): phase A (k-side, online-rescaled stab) computes
// ctx[m][d], ksum[m] entirely in LDS/registers; phase B (q-side) consumes
// them in the same block. 512 threads = 8 waves, static LDS 151,424 B.
// Chunk loop NOT unrolled (icache).
// ---------------------------------------------------------------------------
__global__ __launch_bounds__(512) void favor_fused_kernel(
    const ushort* __restrict__ qn_all, const ushort* __restrict__ kn_all,
    const ushort* __restrict__ v_all, const ushort* __restrict__ projb,
    ushort* __restrict__ Ob)
{
  __shared__ __align__(16) uint8_t smem[151424];
  ushort (*kn_s)[72]      = (ushort(*)[72])(smem);            // [320][72] (qn in B)
  ushort (*vT_s)[328]     = (ushort(*)[328])(smem + 46080);   // [64][328] (ctxT in B)
  ushort (*proj_s)[72]    = (ushort(*)[72])(smem + 88064);    // [272][72]
  ushort (*kpT_s)[40]     = (ushort(*)[40])(smem + 127232);   // [272][40]
  ushort (*qp_s)[16][72]  = (ushort(*)[16][72])(smem + 127232); // [8][16][72] (B)
  float* diag_s = (float*)(smem + 148992);                    // [320]
  float* ksum_s = (float*)(smem + 150272);                    // [272]
  float* red_s  = (float*)(smem + 151360);                    // [8]

  const int tid = threadIdx.x, w = tid >> 6, lane = tid & 63;
  const int bh = blockIdx.x;
  const int b = bh >> 2, h = bh & 3;
  const int r = lane & 15, quad = lane >> 4;
  const int rl = lane >> 3, c8 = lane & 7;

  // ---------------- phase A staging ----------------
  {
    const ushort* knb = kn_all + (size_t)bh * 19200;
    for (int row = w*8 + rl; row < 320; row += 64) {
      uint4 u = {0u,0u,0u,0u};
      if (row < 300) u = *(const uint4*)(knb + row*64 + c8*8);
      *(uint4*)&kn_s[row][c8*8] = u;
      float s = sq8(u);
      s += __shfl_xor(s, 1); s += __shfl_xor(s, 2); s += __shfl_xor(s, 4);
      if (c8 == 0) diag_s[row] = 0.5f * s;
    }
    const ushort* vb = v_all + (size_t)bh * 19200;
    for (int row = w*8 + rl; row < 328; row += 64) {
      uint4 u = {0u,0u,0u,0u};
      if (row < 300) u = *(const uint4*)(vb + row*64 + c8*8);
      const unsigned int uu[4] = {u.x, u.y, u.z, u.w};
#pragma unroll
      for (int p = 0; p < 4; p++) {
        vT_s[c8*8 + 2*p    ][row] = (ushort)(uu[p] & 0xffff);
        vT_s[c8*8 + 2*p + 1][row] = (ushort)(uu[p] >> 16);
      }
    }
    for (int row = w*8 + rl; row < 272; row += 64) {
      uint4 u = {0u,0u,0u,0u};
      if (row < 266) u = *(const uint4*)(projb + row*64 + c8*8);
      *(uint4*)&proj_s[row][c8*8] = u;
    }
  }
  __syncthreads();

  // ---------------- phase A: online chunks of 32 n ----------------
  f32x4 cacc[9];
#pragma unroll
  for (int i = 0; i < 9; i++) cacc[i] = (f32x4){0.f,0.f,0.f,0.f};
  float ksum_acc = 0.f;
  float stab = -3.0e38f;

#pragma unroll 1
  for (int c = 0; c < 10; c++) {
    // dd tiles owned by this wave (<=5), chunk-local max
    f32x4 ddreg[5];
    float cmax = -3.0e38f;
#pragma unroll
    for (int ii = 0; ii < 5; ii++) {
      const int t = w + ii*8;
      if (t < 34) {
        const int tm = t >> 1, tn = c*2 + (t & 1);
        const bf16x8 a0 = *(const bf16x8*)&proj_s[tm*16 + r][quad*8];
        const bf16x8 a1 = *(const bf16x8*)&proj_s[tm*16 + r][32 + quad*8];
        const bf16x8 b0 = *(const bf16x8*)&kn_s[tn*16 + r][quad*8];
        const bf16x8 b1 = *(const bf16x8*)&kn_s[tn*16 + r][32 + quad*8];
        f32x4 acc = (f32x4){0.f,0.f,0.f,0.f};
        acc = MFMA16(a0, b0, acc);
        acc = MFMA16(a1, b1, acc);
        ddreg[ii] = acc;
        const int n = tn*16 + r;
        if (n < 300) {
#pragma unroll
          for (int j = 0; j < 4; j++) {
            const int m = tm*16 + quad*4 + j;
            if (m < 266) cmax = fmaxf(cmax, acc[j]);
          }
        }
      }
    }
#pragma unroll
    for (int off = 32; off; off >>= 1) cmax = fmaxf(cmax, __shfl_xor(cmax, off));
    if (lane == 0) red_s[w] = cmax;
    __syncthreads();
    float bmax = red_s[0];
#pragma unroll
    for (int i = 1; i < 8; i++) bmax = fmaxf(bmax, red_s[i]);
    const float stab_new = fmaxf(stab, bmax);
    const float alpha = __expf(stab - stab_new);   // chunk 0: exp(-inf)=0
    stab = stab_new;
    ksum_acc *= alpha;
#pragma unroll
    for (int i = 0; i < 9; i++)
#pragma unroll
      for (int j = 0; j < 4; j++) cacc[i][j] *= alpha;
    // kp = exp(dd - diag - stab) + eps (valid), else 0 -> kpT_s
#pragma unroll
    for (int ii = 0; ii < 5; ii++) {
      const int t = w + ii*8;
      if (t < 34) {
        const int tm = t >> 1, tnl = t & 1, tn = c*2 + tnl;
        const int n = tn*16 + r;
        const float dgn = diag_s[n];
#pragma unroll
        for (int j = 0; j < 4; j++) {
          const int m = tm*16 + quad*4 + j;
          float kp = 0.f;
          if (n < 300 && m < 266) kp = __expf(ddreg[ii][j] - dgn - stab) + KEPS;
          kpT_s[m][tnl*16 + r] = f2us(kp);
        }
      }
    }
    __syncthreads();
    // ksum row-sums + ctx MFMA accumulate
    if (tid < 272) {
      float rs = 0.f;
#pragma unroll
      for (int kk = 0; kk < 4; kk++) {
        const uint4 u = *(const uint4*)&kpT_s[tid][kk*8];
        const unsigned int uu[4] = {u.x, u.y, u.z, u.w};
#pragma unroll
        for (int p = 0; p < 4; p++)
          rs += bfbits2f((ushort)(uu[p] & 0xffff)) + bfbits2f((ushort)(uu[p] >> 16));
      }
      ksum_acc += rs;
    }
#pragma unroll
    for (int ii = 0; ii < 9; ii++) {
      const int t2 = w + ii*8;
      if (t2 < 68) {
        const int tm = t2 >> 2, td = t2 & 3;
        const bf16x8 aa = *(const bf16x8*)&kpT_s[tm*16 + r][quad*8];
        const bf16x8 bb = *(const bf16x8*)&vT_s[td*16 + r][c*32 + quad*8];
        cacc[ii] = MFMA16(aa, bb, cacc[ii]);
      }
    }
    __syncthreads();
  }

  // ---------------- A->B transition ----------------
  if (tid < 272) ksum_s[tid] = ksum_acc;
  // ctxT overlays vT (stride 328); cols m>=272 hold stale-but-finite bytes,
  // multiplied by explicit qp zeros in phase B.
#pragma unroll
  for (int ii = 0; ii < 9; ii++) {
    const int t2 = w + ii*8;
    if (t2 < 68) {
      const int tm = t2 >> 2, td = t2 & 3;
#pragma unroll
      for (int j = 0; j < 4; j++) {
        const int m = tm*16 + quad*4 + j;
        vT_s[td*16 + r][m] = f2us(cacc[ii][j]);   // ctxT[d][m]
      }
    }
  }
  // stage qn over kn_s (+ diag)
  {
    const ushort* qb = qn_all + (size_t)bh * 19200;
    for (int row = w*8 + rl; row < 320; row += 64) {
      uint4 u = {0u,0u,0u,0u};
      if (row < 300) u = *(const uint4*)(qb + row*64 + c8*8);
      *(uint4*)&kn_s[row][c8*8] = u;
      float s = sq8(u);
      s += __shfl_xor(s, 1); s += __shfl_xor(s, 2); s += __shfl_xor(s, 4);
      if (c8 == 0) diag_s[row] = 0.5f * s;
    }
  }
  __syncthreads();

  // ---------------- phase B: q-side ----------------
#pragma unroll 1
  for (int t = w; t < 19; t += 8) {
    const bf16x8 a0 = *(const bf16x8*)&kn_s[t*16 + r][quad*8];
    const bf16x8 a1 = *(const bf16x8*)&kn_s[t*16 + r][32 + quad*8];
    f32x4 dd[17];
#pragma unroll
    for (int tm = 0; tm < 17; tm++) {
      const bf16x8 b0 = *(const bf16x8*)&proj_s[tm*16 + r][quad*8];
      const bf16x8 b1 = *(const bf16x8*)&proj_s[tm*16 + r][32 + quad*8];
      f32x4 acc = (f32x4){0.f,0.f,0.f,0.f};
      acc = MFMA16(a0, b0, acc);
      acc = MFMA16(a1, b1, acc);
      dd[tm] = acc;
    }
    float mxj[4] = {-3.0e38f, -3.0e38f, -3.0e38f, -3.0e38f};
#pragma unroll
    for (int tm = 0; tm < 17; tm++) {
      if (tm*16 + r < 266) {
#pragma unroll
        for (int j = 0; j < 4; j++) mxj[j] = fmaxf(mxj[j], dd[tm][j]);
      }
    }
#pragma unroll
    for (int off = 1; off < 16; off <<= 1)
#pragma unroll
      for (int j = 0; j < 4; j++) mxj[j] = fmaxf(mxj[j], __shfl_xor(mxj[j], off));
    float dg[4];
#pragma unroll
    for (int j = 0; j < 4; j++) dg[j] = diag_s[t*16 + quad*4 + j];
    float den[4] = {0.f, 0.f, 0.f, 0.f};
#pragma unroll
    for (int tm = 0; tm < 17; tm++) {
      const float ks = ksum_s[tm*16 + r];
      const bool mval = (tm*16 + r < 266);
#pragma unroll
      for (int j = 0; j < 4; j++) {
        const int n = t*16 + quad*4 + j;
        float qp = 0.f;
        if (mval && n < 300) qp = __expf(dd[tm][j] - dg[j] - mxj[j]) + KEPS;
        dd[tm][j] = qp;
        den[j] += qp * ks;
      }
    }
#pragma unroll
    for (int off = 1; off < 16; off <<= 1)
#pragma unroll
      for (int j = 0; j < 4; j++) den[j] += __shfl_xor(den[j], off);
    float dinv[4];
#pragma unroll
    for (int j = 0; j < 4; j++) dinv[j] = 1.0f / den[j];

    // o = qp @ ctxT, K = 320 in 5 groups of 64 (tm>=17 zero)
    f32x4 oacc[4];
#pragma unroll
    for (int td = 0; td < 4; td++) oacc[td] = (f32x4){0.f,0.f,0.f,0.f};
#pragma unroll
    for (int g = 0; g < 5; g++) {
#pragma unroll
      for (int tt = 0; tt < 4; tt++) {
        const int tm = g*4 + tt;
#pragma unroll
        for (int j = 0; j < 4; j++) {
          const ushort us = (tm <= 16) ? f2us(dd[tm][j]) : (ushort)0;
          qp_s[w][quad*4 + j][tt*16 + r] = us;
        }
      }
#pragma unroll
      for (int s = 0; s < 2; s++) {
        const bf16x8 aa = *(const bf16x8*)&qp_s[w][r][s*32 + quad*8];
#pragma unroll
        for (int td = 0; td < 4; td++) {
          const bf16x8 bb = *(const bf16x8*)&vT_s[td*16 + r][g*64 + s*32 + quad*8];
          oacc[td] = MFMA16(aa, bb, oacc[td]);
        }
      }
    }
#pragma unroll
    for (int td = 0; td < 4; td++) {
#pragma unroll
      for (int j = 0; j < 4; j++) {
        const int n = t*16 + quad*4 + j;
        if (n < 300)
          Ob[((size_t)b*300 + n)*256 + h*64 + td*16 + r] = f2us(oacc[td][j] * dinv[j]);
      }
    }
  }
}

// ---------------------------------------------------------------------------
// Mean-pool over N, LayerNorm, 256->128 ReLU, 128->1 sigmoid. Block per batch.
// ---------------------------------------------------------------------------
__global__ __launch_bounds__(256) void head_kernel(
    const float* __restrict__ h, const float* __restrict__ hg,
    const float* __restrict__ hb, const float* __restrict__ wh1,
    const float* __restrict__ bh1, const float* __restrict__ wh2,
    const float* __restrict__ bh2, float* __restrict__ out)
{
  __shared__ float z_s[256];
  __shared__ float hid_s[128];
  __shared__ float red_s[4];
  const int b = blockIdx.x, tid = threadIdx.x;
  const float* hb_ = h + (size_t)b * NSEQ * DIMC;
  float s = 0.f;
  for (int n = 0; n < NSEQ; n++) s += hb_[(size_t)n * DIMC + tid];
  s *= (1.0f / 300.0f);
  float t1 = s;
#pragma unroll
  for (int off = 32; off; off >>= 1) t1 += __shfl_xor(t1, off);
  if ((tid & 63) == 0) red_s[tid >> 6] = t1;
  __syncthreads();
  const float mu = (red_s[0] + red_s[1] + red_s[2] + red_s[3]) * (1.0f/256.0f);
  __syncthreads();
  const float d = s - mu;
  float vv = d * d;
#pragma unroll
  for (int off = 32; off; off >>= 1) vv += __shfl_xor(vv, off);
  if ((tid & 63) == 0) red_s[tid >> 6] = vv;
  __syncthreads();
  const float var = (red_s[0] + red_s[1] + red_s[2] + red_s[3]) * (1.0f/256.0f);
  z_s[tid] = d * rsqrtf(var + 1e-5f) * hg[tid] + hb[tid];
  __syncthreads();
  if (tid < 128) {
    float acc = bh1[tid];
    for (int dd = 0; dd < 256; dd++) acc += z_s[dd] * wh1[dd * 128 + tid];
    hid_s[tid] = fmaxf(acc, 0.f);
  }
  __syncthreads();
  if (tid < 64) {
    float acc = hid_s[tid] * wh2[tid] + hid_s[tid + 64] * wh2[tid + 64];
#pragma unroll
    for (int off = 32; off; off >>= 1) acc += __shfl_xor(acc, off);
    if (tid == 0) {
      const float val = acc + bh2[0];
      out[b] = 1.0f / (1.0f + __expf(-val));
    }
  }
}

// ---------------------------------------------------------------------------
extern "C" void kernel_launch(void* const* d_in, const int* in_sizes, int n_in,
                              void* d_out, int out_size, void* d_ws, size_t ws_size,
                              hipStream_t stream) {
  const float* x    = (const float*)d_in[0];
  const float* w_in = (const float*)d_in[1];
  const float* b_in = (const float*)d_in[2];
  const float* proj = (const float*)d_in[3];
  const float* ln1g = (const float*)d_in[4];
  const float* ln1b = (const float*)d_in[5];
  const float* wq   = (const float*)d_in[6];
  const float* wk   = (const float*)d_in[7];
  const float* wv   = (const float*)d_in[8];
  const float* wo   = (const float*)d_in[9];
  const float* bo   = (const float*)d_in[10];
  const float* ln2g = (const float*)d_in[11];
  const float* ln2b = (const float*)d_in[12];
  const float* w1   = (const float*)d_in[13];
  const float* b1   = (const float*)d_in[14];
  const float* w2   = (const float*)d_in[15];
  const float* b2   = (const float*)d_in[16];
  const float* hg   = (const float*)d_in[17];
  const float* hbp  = (const float*)d_in[18];
  const float* wh1  = (const float*)d_in[19];
  const float* bh1  = (const float*)d_in[20];
  const float* wh2  = (const float*)d_in[21];
  const float* bh2  = (const float*)d_in[22];

  uint8_t* base = (uint8_t*)d_ws;
  float*  h     = (float*)(base);                        // 78,643,200 B
  ushort* yb    = (ushort*)(base + 78643200);            // 39,321,600 B
  ushort* qkv   = (ushort*)(base + 117964800);           // 117,964,800 B
  ushort* ob    = (ushort*)(base + 235929600);           // 39,321,600 B
  ushort* wbuf  = (ushort*)(base + 275251200);           //  3,801,088 B
  ushort* projb = (ushort*)(base + 279052288);           //     68,096 B
  ushort* wopb  = (ushort*)(base + 279120384);           //    262,144 B
  // aliases (disjoint lifetimes):
  ushort* qb = qkv;
  ushort* kb = qkv + 19660800;
  ushort* vb = qkv + 39321600;
  // prep-time scratch for w1T/w2T (qkv region is dead until layer-0 QKV gemm)
  ushort* scr = qkv;   // 4 x 262,144 ushorts

  ushort* w_inT = wbuf;                  // [256][1280]
  ushort* wT0   = wbuf + 327680;

  // --- prep: proj cast + all 13 weight transposes in one launch ---
  cast_bf16_kernel<<<34, 256, 0, stream>>>(proj, projb, 8512);
  TTab tab;
  int nb = 0;
  {
    int idx = 0, basem = 0;
    auto seg = [&](const float* s, ushort* d, int R, int C) {
      tab.s[idx] = TSeg{s, d, R, C, basem};
      basem += (R >> 5) * (C >> 5);
      idx++;
    };
    seg(w_in, w_inT, 1280, 256);
    for (int l = 0; l < 2; l++) {
      ushort* wl = wT0 + (size_t)l * 786432;
      seg(wq + (size_t)l*65536,  wl,          256, 256);
      seg(wk + (size_t)l*65536,  wl + 65536,  256, 256);
      seg(wv + (size_t)l*65536,  wl + 131072, 256, 256);
      seg(wo + (size_t)l*65536,  wl + 196608, 256, 256);
      // w1T/w2T go to scratch; pack_ffn permutes them into wbuf slots
      seg(w1 + (size_t)l*262144, scr + (size_t)l*524288,          256, 1024);
      seg(w2 + (size_t)l*262144, scr + (size_t)l*524288 + 262144, 1024, 256);
    }
    nb = basem;  // 1856
  }
  tcast_all<<<nb, 256, 0, stream>>>(tab);
  for (int l = 0; l < 2; l++) {
    ushort* wl = wT0 + (size_t)l * 786432;
    pack_ffn<<<288, 256, 0, stream>>>(
        scr + (size_t)l*524288, scr + (size_t)l*524288 + 262144,
        wl + 196608,
        wl + 262144, wl + 524288, wopb + (size_t)l*65536);
  }

  // --- h = x @ w_in + b_in (A read as fp32 directly; col-fast grid) ---
  gemm_mfma<0,0,1><<<dim3(2, 600), 256, 0, stream>>>(
      nullptr, x, w_inT, b_in, nullptr, h, nullptr, nullptr, 76800, 256, 1280);

  for (int l = 0; l < 2; l++) {
    ushort* wl = wT0 + (size_t)l * 786432;
    ushort* projL = projb + (size_t)l * 17024;
    ln_kernel<<<19200, 256, 0, stream>>>(h, ln1g + l*256, ln1b + l*256, (__hip_bfloat16*)yb);
    gemm_mfma<4,0,0><<<dim3(6, 600), 256, 0, stream>>>(
        yb, nullptr, wl, nullptr, nullptr, nullptr, nullptr, qkv, 76800, 768, 256);
    favor_fused_kernel<<<1024, 512, 0, stream>>>(qb, kb, vb, projL, ob);
    aoffn_kernel<<<1200, 512, 0, stream>>>(
        h, ob, wopb + (size_t)l*65536, bo + l*256,
        wl + 262144, b1 + (size_t)l*1024, wl + 524288, b2 + (size_t)l*256,
        ln2g + l*256, ln2b + l*256);
  }
  head_kernel<<<256, 256, 0, stream>>>(h, hg, hbp, wh1, bh1, wh2, bh2, (float*)d_out);
}